// Round 12
// baseline (102.144 us; speedup 1.0000x reference)
//
#include <hip/hip_runtime.h>

// DIN encoder. B=8, N=512, D=64, H=64. Three launches:
//   prepW — W1 -> bf16 B-frags of (Wq+Wd),(Wk-Wd) + Wm A-frags (4 blocks)
//   prepX — hq/hk via MFMA (16/wave), X->BF frags (= register A-frags,
//           2 b128 stores), hk scatter, XE; 64 blocks, no LDS, no W1 rereads.
//   k2_main — UNCHANGED from R11 (band LUT + async DMA staging).
// R12 rationale: 5 rounds of main tweaks gave 1-3µs each; prep was still
//   1024 blocks x (48KB W1 reread + LDS weight staging + 48 b128 dot with
//   8-way bank conflicts from the stride-68 layout (68%32=4, m136: ~2.9x)).
//   hq/hk is a 33M-MAC GEMM -> MFMA (G10).
// R3 lesson: tight VGPR caps -> scratch spill. Keep (256,2) on main.
#define NB 8
#define NN 512

// ws layout (float offsets)
#define WS_WMF 0        // Wm A-frag-major fp32 [8 slot][64 lane][8]          4096
#define WS_HQ  4096     // hq fp32 [B*N][64]                                262144
#define WS_BF  266240   // B-frags bf16 [B][32 t][4 c][64 lane][8]   (262144 fl)
#define WS_XE  528384   // enc-X bf16 [B][16 c32][4 nt][64 lane][8]  (131072 fl)
#define WS_WQF 659456   // (Wq+Wd)/(Wk-Wd) bf16 B-frags [16 slot][64][8] (4096 fl)
// total 663552 floats = 2.65 MB

typedef float fx4 __attribute__((ext_vector_type(4)));
typedef short sx8 __attribute__((ext_vector_type(8)));
typedef int   ix4 __attribute__((ext_vector_type(4)));

static __device__ inline unsigned short f2bf(float f) {
    unsigned u = __float_as_uint(f);
    return (unsigned short)((u + 0x7FFFu + ((u >> 16) & 1u)) >> 16);  // RNE
}

// async 16B/lane global -> LDS DMA (gfx950)
static __device__ inline void async_cp16(const void* g, void* l) {
    __builtin_amdgcn_global_load_lds(
        (const __attribute__((address_space(1))) unsigned int*)g,
        (__attribute__((address_space(3))) unsigned int*)l, 16, 0, 0);
}

// ---------------- prepW: weight fragments (4 blocks) ----------------
__global__ __launch_bounds__(256) void prepW(const float* __restrict__ W1,
                                             float* __restrict__ ws) {
    const int t = threadIdx.x, blk = blockIdx.x;
    unsigned short* wqf = (unsigned short*)(ws + WS_WQF);

    // (Wq+Wd) / (Wk-Wd) bf16 B-frags: slot = isK*8 + ht*2 + half
    {
        int e = blk * 256 + t;            // 0..1023
        int slot = e >> 6, lane = e & 63;
        int isK = slot >> 3, ht = (slot >> 1) & 3, half = slot & 1;
        int n = lane & 15, qd = lane >> 4;
        int h = ht * 16 + n, dbase = half * 32 + qd * 8;
        unsigned short u[8];
        #pragma unroll
        for (int j = 0; j < 8; ++j) {
            int d = dbase + j;
            float wq = W1[h * 256 + d];
            float wk = W1[h * 256 + 64 + d];
            float wd = W1[h * 256 + 128 + d];
            u[j] = f2bf(isK ? (wk - wd) : (wq + wd));
        }
        uint4 o;
        o.x = (unsigned)u[0] | ((unsigned)u[1] << 16);
        o.y = (unsigned)u[2] | ((unsigned)u[3] << 16);
        o.z = (unsigned)u[4] | ((unsigned)u[5] << 16);
        o.w = (unsigned)u[6] | ((unsigned)u[7] << 16);
        ((uint4*)wqf)[e] = o;
    }

    // Wm A-frag-major fp32 (blocks 0..1)
    if (blk < 2) {
        float* wmf = ws + WS_WMF;
        int e = blk * 256 + t;            // 0..511
        int slot = e >> 6, lane = e & 63;
        int ht = slot >> 1, hf = slot & 1;
        int m = lane & 15, qd = lane >> 4;
        int h = ht * 16 + m;
        int dbase = hf * 32 + qd * 8;
        #pragma unroll
        for (int j = 0; j < 8; ++j)
            wmf[e * 8 + j] = W1[h * 256 + 192 + dbase + j];
    }
}

// ---------------- prepX: hq/hk via MFMA + BF/XE staging (64 blocks) --------
__global__ __launch_bounds__(256) void prepX(const float* __restrict__ x,
                                             const float* __restrict__ vm,
                                             const float* __restrict__ b1,
                                             float* __restrict__ ws) {
    const int t = threadIdx.x;
    const int w = t >> 6, lane = t & 63;
    const int n = lane & 15, quad = lane >> 4;
    const int blk = blockIdx.x;
    const int b   = blk >> 3;             // batch
    const int tb  = (blk & 7) * 4;        // first of 4 key-tiles
    const int tile = tb + w;              // this wave's 16-row tile

    const unsigned short* wqf = (const unsigned short*)(ws + WS_WQF);
    unsigned short* bfp = (unsigned short*)(ws + WS_BF);
    unsigned short* xep = (unsigned short*)(ws + WS_XE);
    float* hqp = ws + WS_HQ;

    // x rows as bf16 A-frags: A[m=lane&15 -> row][k = half*32 + quad*8 + j]
    sx8 ax0, ax1;
    {
        const float* xp = x + ((b * 512 + tile * 16 + n) * 64 + quad * 8);
        fx4 a0 = *(const fx4*)xp;
        fx4 a1 = *(const fx4*)(xp + 4);
        fx4 a2 = *(const fx4*)(xp + 32);
        fx4 a3 = *(const fx4*)(xp + 36);
        #pragma unroll
        for (int j = 0; j < 4; ++j) {
            ax0[j] = (short)f2bf(a0[j]); ax0[4 + j] = (short)f2bf(a1[j]);
            ax1[j] = (short)f2bf(a2[j]); ax1[4 + j] = (short)f2bf(a3[j]);
        }
    }

    // BF chunks 0/1 ARE the A-frag layout -> two b128 stores
    *(uint4*)(bfp + ((((b * 32 + tile) * 4 + 0) * 64 + lane) << 3)) =
        __builtin_bit_cast(uint4, ax0);
    *(uint4*)(bfp + ((((b * 32 + tile) * 4 + 1) * 64 + lane) << 3)) =
        __builtin_bit_cast(uint4, ax1);

    // hq/hk MFMAs: B-frags from wqf (L2-resident, 16 KB)
    #pragma unroll
    for (int ht = 0; ht < 4; ++ht) {
        sx8 bq0 = *(const sx8*)(wqf + ((ht * 2 + 0) << 9) + lane * 8);
        sx8 bq1 = *(const sx8*)(wqf + ((ht * 2 + 1) << 9) + lane * 8);
        sx8 bk0 = *(const sx8*)(wqf + ((8 + ht * 2 + 0) << 9) + lane * 8);
        sx8 bk1 = *(const sx8*)(wqf + ((8 + ht * 2 + 1) << 9) + lane * 8);

        float bv = b1[ht * 16 + n];
        fx4 hqa = (fx4){bv, bv, bv, bv};
        hqa = __builtin_amdgcn_mfma_f32_16x16x32_bf16(ax0, bq0, hqa, 0, 0, 0);
        hqa = __builtin_amdgcn_mfma_f32_16x16x32_bf16(ax1, bq1, hqa, 0, 0, 0);
        fx4 hka = (fx4){0.f, 0.f, 0.f, 0.f};
        hka = __builtin_amdgcn_mfma_f32_16x16x32_bf16(ax0, bk0, hka, 0, 0, 0);
        hka = __builtin_amdgcn_mfma_f32_16x16x32_bf16(ax1, bk1, hka, 0, 0, 0);

        // hq store: row = tile*16 + quad*4 + r, h = ht*16 + n
        #pragma unroll
        for (int r = 0; r < 4; ++r)
            hqp[(b * 512 + tile * 16 + quad * 4 + r) * 64 + ht * 16 + n] = hqa[r];

        // hk scatter into BF chunk c = 2 + (ht>>1)
        int c   = 2 + (ht >> 1);
        int qd2 = (((ht & 1) * 16 + n) >> 3);   // (h&31)>>3
        int j   = n & 7;
        #pragma unroll
        for (int r = 0; r < 4; ++r) {
            int nn = quad * 4 + r;
            bfp[((((b * 32 + tile) * 4 + c) * 64 + (qd2 * 16 + nn)) << 3) + j] =
                f2bf(hka[r]);
        }
    }

    // XE (masked x bf16, enc B-frag layout) — same pattern as before,
    // looped over this block's 4 tiles
    #pragma unroll 1
    for (int i = 0; i < 4; ++i) {
        int t5 = tb + i;
        int c32 = t5 >> 1, half = t5 & 1;
        int nt = t >> 6, r = t & 63;
        int L = half * 32 + (r & 31);
        int j0 = (r >> 5) * 4;
        int qd3 = L >> 4, nn3 = L & 15;
        unsigned short u[4];
        #pragma unroll
        for (int ii = 0; ii < 4; ++ii) {
            int key = c32 * 32 + qd3 * 8 + j0 + ii;
            float v = x[(b * 512 + key) * 64 + nt * 16 + nn3] * vm[b * 512 + key];
            u[ii] = f2bf(v);
        }
        uint2 o;
        o.x = (unsigned)u[0] | ((unsigned)u[1] << 16);
        o.y = (unsigned)u[2] | ((unsigned)u[3] << 16);
        *(uint2*)(xep + (((((b * 16 + c32) * 4 + nt) * 64 + L) << 3) + j0)) = o;
    }
}

// ------- main: 1024 blocks, band LUT balanced, async DMA staging -------
__global__ __launch_bounds__(256, 2) void k2_main(const float* __restrict__ x,
                                                  const float* __restrict__ prelu_a,
                                                  const float* __restrict__ W2,
                                                  const float* __restrict__ b2,
                                                  const float* __restrict__ ws,
                                                  float* __restrict__ out) {
    const int tid  = threadIdx.x;
    const int lane = tid & 63;
    const int w    = tid >> 6;            // 0..3
    const int blk  = blockIdx.x;
    // band LUT: columns {j, j+4, j+8, j+12} sum to 30 -> every CU's 4
    // resident blocks (stride-256 pattern) total 34 rounds. Heavy first.
    const int band = (int)((0x4501763298DCABEFULL >> ((blk >> 6) << 2)) & 0xF);
    const int rest = blk & 63;
    const int b    = rest >> 3;
    const int s    = rest & 7;            // 4-query slice within band
    const int n    = lane & 15, quad = lane >> 4;
    const int q    = band * 32 + s * 4 + w;
    const int bq   = b * 512 + q;
    const int cmax = band;                // q>>5 == band by construction

    const float* wmf = ws + WS_WMF;
    const float* hq  = ws + WS_HQ;
    const unsigned short* bfp = (const unsigned short*)(ws + WS_BF);
    const unsigned short* xep = (const unsigned short*)(ws + WS_XE);

    const float pa  = prelu_a[0];
    const float b2v = b2[0];

    __shared__ uint4 bufS[2][512];     // score frags: 8 KB per buffer
    __shared__ uint4 bufE[2][256];     // enc-X frags: 4 KB per buffer
    __shared__ unsigned strip[4][16];  // per-wave packed score strip

    // W2 (fx4), one-hot, perm sel
    fx4 w2v[4];
    #pragma unroll
    for (int ht = 0; ht < 4; ++ht)
        w2v[ht] = *(const fx4*)(W2 + ht * 16 + quad * 4);
    sx8 oh[4];
    #pragma unroll
    for (int ht = 0; ht < 4; ++ht) {
        sx8 a;
        #pragma unroll
        for (int jj = 0; jj < 8; ++jj) {
            int hp = (ht >> 1) * 32 + quad * 8 + jj;
            a[jj] = (hp == ht * 16 + n) ? (short)0x3F80 : (short)0;
        }
        oh[ht] = a;
    }
    const unsigned sel = (quad < 2) ? 0x05040100u : 0x07060302u;

    // per-query prologue
    fx4 hqv[4];
    #pragma unroll
    for (int ht = 0; ht < 4; ++ht)
        hqv[ht] = *(const fx4*)(hq + bq * 64 + ht * 16 + quad * 4);
    float xq[2][8];
    {
        const float* xp = x + bq * 64 + quad * 8;
        fx4 t0 = *(const fx4*)xp;
        fx4 t1 = *(const fx4*)(xp + 4);
        fx4 t2 = *(const fx4*)(xp + 32);
        fx4 t3 = *(const fx4*)(xp + 36);
        #pragma unroll
        for (int jj = 0; jj < 4; ++jj) {
            xq[0][jj] = t0[jj]; xq[0][4 + jj] = t1[jj];
            xq[1][jj] = t2[jj]; xq[1][4 + jj] = t3[jj];
        }
    }
    sx8 afrag[4][2];
    #pragma unroll
    for (int ht = 0; ht < 4; ++ht)
        #pragma unroll
        for (int hf = 0; hf < 2; ++hf) {
            const float* wp = wmf + (((ht * 2 + hf) * 64 + lane) << 3);
            fx4 w0 = *(const fx4*)wp;
            fx4 w1 = *(const fx4*)(wp + 4);
            sx8 a;
            #pragma unroll
            for (int jj = 0; jj < 4; ++jj) {
                a[jj]     = (short)f2bf(w0[jj] * xq[hf][jj]);
                a[4 + jj] = (short)f2bf(w1[jj] * xq[hf][4 + jj]);
            }
            afrag[ht][hf] = a;
        }

    fx4 eacc[4];
    #pragma unroll
    for (int nt = 0; nt < 4; ++nt) eacc[nt] = (fx4){0.f, 0.f, 0.f, 0.f};

    // stage chunk 0 via async DMA; __syncthreads drains vmcnt
    {
        const uint4* sS = (const uint4*)(bfp + (unsigned)(b * 32) * 2048);
        const uint4* sE = (const uint4*)(xep + (unsigned)(b * 16) * 2048);
        async_cp16(sS + tid,       &bufS[0][tid]);
        async_cp16(sS + tid + 256, &bufS[0][tid + 256]);
        async_cp16(sE + tid,       &bufE[0][tid]);
    }
    __syncthreads();

    #pragma unroll 1
    for (int c = 0; c <= cmax; ++c) {
        // async-stage next chunk into the back buffer (DMA, no VGPRs)
        if (c < cmax) {
            const int p2 = (c + 1) & 1;
            const uint4* sS = (const uint4*)(bfp + (unsigned)(b * 32 + 2 * (c + 1)) * 2048);
            const uint4* sE = (const uint4*)(xep + (unsigned)(b * 16 + c + 1) * 2048);
            async_cp16(sS + tid,       &bufS[p2][tid]);
            async_cp16(sS + tid + 256, &bufS[p2][tid + 256]);
            async_cp16(sE + tid,       &bufE[p2][tid]);
        }

        const int p = c & 1;
        const unsigned short* ls = (const unsigned short*)&bufS[p][0] + lane * 8;
        sx8 fa0 = *(const sx8*)(ls);
        sx8 fa1 = *(const sx8*)(ls + 512);
        sx8 fa2 = *(const sx8*)(ls + 1024);
        sx8 fa3 = *(const sx8*)(ls + 1536);
        sx8 fb0 = *(const sx8*)(ls + 2048);
        sx8 fb1 = *(const sx8*)(ls + 2560);
        sx8 fb2 = *(const sx8*)(ls + 3072);
        sx8 fb3 = *(const sx8*)(ls + 3584);

        fx4 accA[4], accB[4];
        #pragma unroll
        for (int ht = 0; ht < 4; ++ht) { accA[ht] = hqv[ht]; accB[ht] = hqv[ht]; }
        #pragma unroll
        for (int ht = 0; ht < 4; ++ht) {
            accA[ht] = __builtin_amdgcn_mfma_f32_16x16x32_bf16(afrag[ht][0], fa0, accA[ht], 0, 0, 0);
            accB[ht] = __builtin_amdgcn_mfma_f32_16x16x32_bf16(afrag[ht][0], fb0, accB[ht], 0, 0, 0);
        }
        #pragma unroll
        for (int ht = 0; ht < 4; ++ht) {
            accA[ht] = __builtin_amdgcn_mfma_f32_16x16x32_bf16(afrag[ht][1], fa1, accA[ht], 0, 0, 0);
            accB[ht] = __builtin_amdgcn_mfma_f32_16x16x32_bf16(afrag[ht][1], fb1, accB[ht], 0, 0, 0);
        }
        #pragma unroll
        for (int ht = 0; ht < 4; ++ht) {
            accA[ht] = __builtin_amdgcn_mfma_f32_16x16x32_bf16(oh[ht], (ht < 2) ? fa2 : fa3, accA[ht], 0, 0, 0);
            accB[ht] = __builtin_amdgcn_mfma_f32_16x16x32_bf16(oh[ht], (ht < 2) ? fb2 : fb3, accB[ht], 0, 0, 0);
        }

        // PReLU(z)=max(z, pa*z); W2 dot as fx4; quad-reduce
        fx4 s0v = (fx4){0.f, 0.f, 0.f, 0.f};
        fx4 s1v = (fx4){0.f, 0.f, 0.f, 0.f};
        #pragma unroll
        for (int ht = 0; ht < 4; ++ht) {
            fx4 za = accA[ht], zb = accB[ht];
            fx4 ta = __builtin_elementwise_max(za, za * pa);
            fx4 tb = __builtin_elementwise_max(zb, zb * pa);
            s0v = ta * w2v[ht] + s0v;
            s1v = tb * w2v[ht] + s1v;
        }
        float s0 = (s0v[0] + s0v[1]) + (s0v[2] + s0v[3]);
        float s1 = (s1v[0] + s1v[1]) + (s1v[2] + s1v[3]);
        s0 += __shfl_xor(s0, 16, 64);
        s0 += __shfl_xor(s0, 32, 64);
        s1 += __shfl_xor(s1, 16, 64);
        s1 += __shfl_xor(s1, 32, 64);
        int k0 = c * 32 + n;
        s0 = (k0 <= q)      ? s0 + b2v : 0.f;
        s1 = (k0 + 16 <= q) ? s1 + b2v : 0.f;

        // scores -> A-frag via per-wave LDS strip (in-wave order)
        unsigned packed = (unsigned)f2bf(s0) | ((unsigned)f2bf(s1) << 16);
        if (quad == 0) strip[w][n] = packed;
        const unsigned* sp = &strip[w][(quad & 1) * 8];
        uint4 wv0 = *(const uint4*)sp;
        uint4 wv1 = *(const uint4*)(sp + 4);
        ix4 sw_;
        sw_[0] = (int)__builtin_amdgcn_perm(wv0.y, wv0.x, sel);
        sw_[1] = (int)__builtin_amdgcn_perm(wv0.w, wv0.z, sel);
        sw_[2] = (int)__builtin_amdgcn_perm(wv1.y, wv1.x, sel);
        sw_[3] = (int)__builtin_amdgcn_perm(wv1.w, wv1.z, sel);
        sx8 sfrag = __builtin_bit_cast(sx8, sw_);

        const unsigned short* le = (const unsigned short*)&bufE[p][0] + lane * 8;
        sx8 e0 = *(const sx8*)(le);
        sx8 e1 = *(const sx8*)(le + 512);
        sx8 e2 = *(const sx8*)(le + 1024);
        sx8 e3 = *(const sx8*)(le + 1536);

        eacc[0] = __builtin_amdgcn_mfma_f32_16x16x32_bf16(sfrag, e0, eacc[0], 0, 0, 0);
        eacc[1] = __builtin_amdgcn_mfma_f32_16x16x32_bf16(sfrag, e1, eacc[1], 0, 0, 0);
        eacc[2] = __builtin_amdgcn_mfma_f32_16x16x32_bf16(sfrag, e2, eacc[2], 0, 0, 0);
        eacc[3] = __builtin_amdgcn_mfma_f32_16x16x32_bf16(sfrag, e3, eacc[3], 0, 0, 0);

        // barrier: drains DMA (vmcnt) + protects buffer swap
        __syncthreads();
    }

    // all m-rows identical; lane's d = quad*16 + n = lane
    float ov = eacc[0][0];
    if (quad == 1) ov = eacc[1][0];
    if (quad == 2) ov = eacc[2][0];
    if (quad == 3) ov = eacc[3][0];
    out[bq * 64 + lane] = ov;
}

extern "C" void kernel_launch(void* const* d_in, const int* in_sizes, int n_in,
                              void* d_out, int out_size, void* d_ws, size_t ws_size,
                              hipStream_t stream) {
    const float* x   = (const float*)d_in[1];
    const float* vmk = (const float*)d_in[2];
    const float* W1  = (const float*)d_in[3];
    const float* b1  = (const float*)d_in[4];
    const float* pa  = (const float*)d_in[5];
    const float* W2  = (const float*)d_in[6];
    const float* b2  = (const float*)d_in[7];
    float* ws  = (float*)d_ws;
    float* out = (float*)d_out;

    hipLaunchKernelGGL(prepW, dim3(4), dim3(256), 0, stream, W1, ws);
    hipLaunchKernelGGL(prepX, dim3(64), dim3(256), 0, stream, x, vmk, b1, ws);
    hipLaunchKernelGGL(k2_main, dim3(1024), dim3(256), 0, stream,
                       x, pa, W2, b2, ws, out);
}